// Round 1
// baseline (683.207 us; speedup 1.0000x reference)
//
#include <hip/hip_runtime.h>
#include <math.h>

#define N_ROWS 65536
#define Q 4096
#define E 64
#define NCH 4            // Q split across blocks for occupancy
#define QPC (Q / NCH)    // 1024 codes per chunk

// Replicates numpy pairwise_sum of v[i]*v[i] for n=64:
// r[0..7]=p[0..7]; stripes of 8; final ((r0+r1)+(r2+r3))+((r4+r5)+(r6+r7)).
// fp contract(off): numpy multiplies the array first, then sums — no FMA fusion.
__device__ __forceinline__ float pairwise_sq_sum64(const float* v) {
#pragma clang fp contract(off)
  float r[8];
#pragma unroll
  for (int j = 0; j < 8; ++j) r[j] = v[j] * v[j];
#pragma unroll
  for (int i = 8; i < 64; i += 8) {
#pragma unroll
    for (int j = 0; j < 8; ++j) {
      float p = v[i + j] * v[i + j];
      r[j] = r[j] + p;
    }
  }
  return ((r[0] + r[1]) + (r[2] + r[3])) + ((r[4] + r[5]) + (r[6] + r[7]));
}

// w_sq[q] = numpy-pairwise sum(w[q]^2)
__global__ __launch_bounds__(256) void wsq_kernel(const float* __restrict__ w,
                                                  float* __restrict__ wsq) {
  const int q = blockIdx.x * 256 + threadIdx.x;
  float v[E];
  const float4* p = (const float4*)(w + (size_t)q * E);
#pragma unroll
  for (int k = 0; k < 16; ++k) ((float4*)v)[k] = p[k];
  wsq[q] = pairwise_sq_sum64(v);
}

// One thread per row; each block handles one Q-chunk of 1024 codes.
// w/wsq accesses are wave-uniform -> scalar loads feeding v_fma v,s,v.
// Dot product: sequential FMA over k (matches BLAS sgemm microkernel order),
// 4 independent j-chains for ILP.
__global__ __launch_bounds__(256) void dist_kernel(
    const float* __restrict__ x, const float* __restrict__ w,
    const float* __restrict__ wsq, float* __restrict__ pmin,
    int* __restrict__ pidx) {
  const int b = blockIdx.x;
  const int qc = b & (NCH - 1);
  const int row = (b >> 2) * 256 + threadIdx.x;

  float hv[E];
  const float4* xp = (const float4*)(x + (size_t)row * E);
#pragma unroll
  for (int k = 0; k < 16; ++k) ((float4*)hv)[k] = xp[k];
  const float hsq = pairwise_sq_sum64(hv);

  float dmin = INFINITY;
  int best = 0;
  const int jbase = qc * QPC;
  const float* wp = w + (size_t)jbase * E;

  for (int j0 = 0; j0 < QPC; j0 += 4) {
    const float* w0 = wp + (size_t)j0 * E;
    float a0 = 0.f, a1 = 0.f, a2 = 0.f, a3 = 0.f;
#pragma unroll
    for (int k = 0; k < E; ++k) {
      const float h = hv[k];
      a0 = fmaf(w0[k], h, a0);
      a1 = fmaf(w0[E + k], h, a1);
      a2 = fmaf(w0[2 * E + k], h, a2);
      a3 = fmaf(w0[3 * E + k], h, a3);
    }
    // dist = RN( RN(hsq + wsq[j]) - 2*dot )  (2*dot exact; fmaf rounds once)
    {
      const float t = hsq + wsq[jbase + j0];
      const float d = fmaf(-2.f, a0, t);
      if (d < dmin) { dmin = d; best = jbase + j0; }
    }
    {
      const float t = hsq + wsq[jbase + j0 + 1];
      const float d = fmaf(-2.f, a1, t);
      if (d < dmin) { dmin = d; best = jbase + j0 + 1; }
    }
    {
      const float t = hsq + wsq[jbase + j0 + 2];
      const float d = fmaf(-2.f, a2, t);
      if (d < dmin) { dmin = d; best = jbase + j0 + 2; }
    }
    {
      const float t = hsq + wsq[jbase + j0 + 3];
      const float d = fmaf(-2.f, a3, t);
      if (d < dmin) { dmin = d; best = jbase + j0 + 3; }
    }
  }
  pmin[(size_t)qc * N_ROWS + row] = dmin;
  pidx[(size_t)qc * N_ROWS + row] = best;
}

// Combine the NCH partial argmins (strict < keeps lowest j on ties, matching
// numpy first-occurrence), gather codeword, write idx as float.
__global__ __launch_bounds__(256) void gather_kernel(
    const float* __restrict__ w, const float* __restrict__ pmin,
    const int* __restrict__ pidx, float* __restrict__ out) {
  const int t = blockIdx.x * 256 + threadIdx.x;
  const int row = t >> 4;
  const int part = t & 15;

  float dmin = INFINITY;
  int best = 0;
#pragma unroll
  for (int c = 0; c < NCH; ++c) {
    const float d = pmin[(size_t)c * N_ROWS + row];
    const int i = pidx[(size_t)c * N_ROWS + row];
    if (d < dmin) { dmin = d; best = i; }
  }
  const float4 v = ((const float4*)(w + (size_t)best * E))[part];
  ((float4*)(out + (size_t)row * E))[part] = v;
  if (part == 0) out[(size_t)N_ROWS * E + row] = (float)best;
}

extern "C" void kernel_launch(void* const* d_in, const int* in_sizes, int n_in,
                              void* d_out, int out_size, void* d_ws,
                              size_t ws_size, hipStream_t stream) {
  const float* x = (const float*)d_in[0];
  const float* w = (const float*)d_in[1];
  float* out = (float*)d_out;

  // workspace layout: wsq[4096] | pmin[NCH][N_ROWS] | pidx[NCH][N_ROWS]
  float* wsq = (float*)d_ws;
  float* pmin = wsq + Q;
  int* pidx = (int*)(pmin + (size_t)NCH * N_ROWS);

  wsq_kernel<<<Q / 256, 256, 0, stream>>>(w, wsq);
  dist_kernel<<<(N_ROWS / 256) * NCH, 256, 0, stream>>>(x, w, wsq, pmin, pidx);
  gather_kernel<<<(N_ROWS * 16) / 256, 256, 0, stream>>>(w, pmin, pidx, out);
}

// Round 2
// 531.828 us; speedup vs baseline: 1.2846x; 1.2846x over previous
//
#include <hip/hip_runtime.h>
#include <math.h>

#define N_ROWS 65536
#define Q 4096
#define E 64
#define NCH 4            // Q split across blocks
#define QPC (Q / NCH)    // 1024 codes per chunk
#define R 2              // rows per thread

// Replicates numpy pairwise_sum of v[i]*v[i] for n=64:
// r[0..7]=p[0..7]; stripes of 8; final ((r0+r1)+(r2+r3))+((r4+r5)+(r6+r7)).
// fp contract(off): numpy multiplies the array first, then sums — no FMA fusion.
__device__ __forceinline__ float pairwise_sq_sum64(const float* v) {
#pragma clang fp contract(off)
  float r[8];
#pragma unroll
  for (int j = 0; j < 8; ++j) r[j] = v[j] * v[j];
#pragma unroll
  for (int i = 8; i < 64; i += 8) {
#pragma unroll
    for (int j = 0; j < 8; ++j) {
      float p = v[i + j] * v[i + j];
      r[j] = r[j] + p;
    }
  }
  return ((r[0] + r[1]) + (r[2] + r[3])) + ((r[4] + r[5]) + (r[6] + r[7]));
}

// SROA-safe row load: float4 temporaries, elementwise stores w/ constant idx.
__device__ __forceinline__ void load_row64(const float* __restrict__ src,
                                           float* dst) {
  const float4* p = (const float4*)src;
#pragma unroll
  for (int k4 = 0; k4 < 16; ++k4) {
    const float4 t = p[k4];
    dst[4 * k4 + 0] = t.x;
    dst[4 * k4 + 1] = t.y;
    dst[4 * k4 + 2] = t.z;
    dst[4 * k4 + 3] = t.w;
  }
}

// w_sq[q] = numpy-pairwise sum(w[q]^2)
__global__ __launch_bounds__(256) void wsq_kernel(const float* __restrict__ w,
                                                  float* __restrict__ wsq) {
  const int q = blockIdx.x * 256 + threadIdx.x;
  float v[E];
  load_row64(w + (size_t)q * E, v);
  wsq[q] = pairwise_sq_sum64(v);
}

// R=2 rows per thread; each block handles one Q-chunk of 1024 codes.
// w/wsq accesses are wave-uniform -> scalar loads feeding v_fma v,s,v.
// Dot product: sequential fmaf over k ascending (matches BLAS sgemm k-order,
// validated absmax=0 in round 1); 4 codes x 2 rows = 8 independent chains.
__global__ __launch_bounds__(256, 2) void dist_kernel(
    const float* __restrict__ x, const float* __restrict__ w,
    const float* __restrict__ wsq, float* __restrict__ pmin,
    int* __restrict__ pidx) {
  const int b = blockIdx.x;          // 512 blocks: 128 row-groups x NCH
  const int qc = b & (NCH - 1);
  const int row0 = (b >> 2) * (256 * R) + threadIdx.x;  // and row0+256

  float hv0[E], hv1[E];
  load_row64(x + (size_t)row0 * E, hv0);
  load_row64(x + (size_t)(row0 + 256) * E, hv1);
  const float hsq0 = pairwise_sq_sum64(hv0);
  const float hsq1 = pairwise_sq_sum64(hv1);

  float dmin0 = INFINITY, dmin1 = INFINITY;
  int best0 = 0, best1 = 0;
  const int jbase = qc * QPC;
  const float* wp = w + (size_t)jbase * E;

  for (int j0 = 0; j0 < QPC; j0 += 4) {
    const float* w0 = wp + (size_t)j0 * E;
    float a00 = 0.f, a01 = 0.f, a02 = 0.f, a03 = 0.f;
    float a10 = 0.f, a11 = 0.f, a12 = 0.f, a13 = 0.f;
#pragma unroll
    for (int k = 0; k < E; ++k) {
      const float wk0 = w0[k];
      const float wk1 = w0[E + k];
      const float wk2 = w0[2 * E + k];
      const float wk3 = w0[3 * E + k];
      const float h0 = hv0[k];
      const float h1 = hv1[k];
      a00 = fmaf(wk0, h0, a00);
      a01 = fmaf(wk1, h0, a01);
      a02 = fmaf(wk2, h0, a02);
      a03 = fmaf(wk3, h0, a03);
      a10 = fmaf(wk0, h1, a10);
      a11 = fmaf(wk1, h1, a11);
      a12 = fmaf(wk2, h1, a12);
      a13 = fmaf(wk3, h1, a13);
    }
    // dist = RN( RN(hsq + wsq[j]) - 2*dot )  (2*dot exact; fmaf rounds once).
    // Strict < with ascending j == numpy first-occurrence argmin.
    const float ws0 = wsq[jbase + j0];
    const float ws1 = wsq[jbase + j0 + 1];
    const float ws2 = wsq[jbase + j0 + 2];
    const float ws3 = wsq[jbase + j0 + 3];
    {
      const float d = fmaf(-2.f, a00, hsq0 + ws0);
      if (d < dmin0) { dmin0 = d; best0 = jbase + j0; }
    }
    {
      const float d = fmaf(-2.f, a01, hsq0 + ws1);
      if (d < dmin0) { dmin0 = d; best0 = jbase + j0 + 1; }
    }
    {
      const float d = fmaf(-2.f, a02, hsq0 + ws2);
      if (d < dmin0) { dmin0 = d; best0 = jbase + j0 + 2; }
    }
    {
      const float d = fmaf(-2.f, a03, hsq0 + ws3);
      if (d < dmin0) { dmin0 = d; best0 = jbase + j0 + 3; }
    }
    {
      const float d = fmaf(-2.f, a10, hsq1 + ws0);
      if (d < dmin1) { dmin1 = d; best1 = jbase + j0; }
    }
    {
      const float d = fmaf(-2.f, a11, hsq1 + ws1);
      if (d < dmin1) { dmin1 = d; best1 = jbase + j0 + 1; }
    }
    {
      const float d = fmaf(-2.f, a12, hsq1 + ws2);
      if (d < dmin1) { dmin1 = d; best1 = jbase + j0 + 2; }
    }
    {
      const float d = fmaf(-2.f, a13, hsq1 + ws3);
      if (d < dmin1) { dmin1 = d; best1 = jbase + j0 + 3; }
    }
  }
  pmin[(size_t)qc * N_ROWS + row0] = dmin0;
  pidx[(size_t)qc * N_ROWS + row0] = best0;
  pmin[(size_t)qc * N_ROWS + row0 + 256] = dmin1;
  pidx[(size_t)qc * N_ROWS + row0 + 256] = best1;
}

// Combine the NCH partial argmins (strict < keeps lowest j on ties, matching
// numpy first-occurrence), gather codeword, write idx as float.
__global__ __launch_bounds__(256) void gather_kernel(
    const float* __restrict__ w, const float* __restrict__ pmin,
    const int* __restrict__ pidx, float* __restrict__ out) {
  const int t = blockIdx.x * 256 + threadIdx.x;
  const int row = t >> 4;
  const int part = t & 15;

  float dmin = INFINITY;
  int best = 0;
#pragma unroll
  for (int c = 0; c < NCH; ++c) {
    const float d = pmin[(size_t)c * N_ROWS + row];
    const int i = pidx[(size_t)c * N_ROWS + row];
    if (d < dmin) { dmin = d; best = i; }
  }
  const float4 v = ((const float4*)(w + (size_t)best * E))[part];
  ((float4*)(out + (size_t)row * E))[part] = v;
  if (part == 0) out[(size_t)N_ROWS * E + row] = (float)best;
}

extern "C" void kernel_launch(void* const* d_in, const int* in_sizes, int n_in,
                              void* d_out, int out_size, void* d_ws,
                              size_t ws_size, hipStream_t stream) {
  const float* x = (const float*)d_in[0];
  const float* w = (const float*)d_in[1];
  float* out = (float*)d_out;

  // workspace layout: wsq[4096] | pmin[NCH][N_ROWS] | pidx[NCH][N_ROWS]
  float* wsq = (float*)d_ws;
  float* pmin = wsq + Q;
  int* pidx = (int*)(pmin + (size_t)NCH * N_ROWS);

  wsq_kernel<<<Q / 256, 256, 0, stream>>>(w, wsq);
  dist_kernel<<<(N_ROWS / (256 * R)) * NCH, 256, 0, stream>>>(x, w, wsq, pmin,
                                                              pidx);
  gather_kernel<<<(N_ROWS * 16) / 256, 256, 0, stream>>>(w, pmin, pidx, out);
}